// Round 2
// baseline (21594.078 us; speedup 1.0000x reference)
//
#include <hip/hip_runtime.h>

// ---------------------------------------------------------------------------
// SimpleGRU on MI355X (gfx950).
// Dtype decision (round-2): reference declares jnp.float32 everywhere; round-1
// NaN forensics prove float inputs are f32 (bf16-misread of w_out's mantissa
// halves was the only possible NaN source). Comparison is done in bf16 domain
// (threshold 4.125e-2 = 2% of ref absmax) but buffers are f32.
//   d_in[0] seq     int32 [512][64]
//   d_in[1] lengths int32 [64]
//   d_in[2] emb     f32   [32000][256]
//   d_in[3] w_ih    f32   [1536][256]
//   d_in[4] w_hh    f32   [1536][512]
//   d_in[5] b_ih    f32   [1536]
//   d_in[6] b_hh    f32   [1536]
//   d_in[7] w_out   f32   [5][512]
//   d_in[8] b_out   f32   [5]
//   d_out           f32   [64][5]  (log_softmax)
// ws: xg bf16 [64][512][1536] (100,663,296 B) + w_hh as f16 (1,572,864 B)
// ---------------------------------------------------------------------------

typedef unsigned short ushort_t;
typedef short short8    __attribute__((ext_vector_type(8)));
typedef float floatx4   __attribute__((ext_vector_type(4)));
typedef _Float16 half8  __attribute__((ext_vector_type(8)));
typedef _Float16 half2v __attribute__((ext_vector_type(2)));

#define SEQL 512
#define BATCH 64
#define EMBD 256
#define HID 512
#define G3 1536
#define NOUT 5

__device__ __forceinline__ float bf2f(ushort_t v){
  union { unsigned u; float f; } x; x.u = ((unsigned)v) << 16; return x.f;
}
__device__ __forceinline__ ushort_t f2bf(float f){
  unsigned u = __float_as_uint(f);
  unsigned r = (u + 0x7FFFu + ((u >> 16) & 1u)) >> 16;
  return (ushort_t)r;
}
__device__ __forceinline__ float sigm(float x){
  x = fminf(fmaxf(x, -20.f), 20.f);
  return 1.f / (1.f + __expf(-x));
}
__device__ __forceinline__ float tanh_c(float x){
  x = fminf(fmaxf(x, -10.f), 10.f);
  float e = __expf(2.f * x);
  return (e - 1.f) / (e + 1.f);
}
__device__ __forceinline__ float dot2f(half2v a, half2v b, float c){
#if __has_builtin(__builtin_amdgcn_fdot2)
  return __builtin_amdgcn_fdot2(a, b, c, false);
#else
  return c + (float)a[0]*(float)b[0] + (float)a[1]*(float)b[1];
#endif
}

// --- K0: convert w_hh f32 -> f16 (values |x| <= 1/sqrt(512), exact-ish) ---
__global__ __launch_bounds__(256) void gru_cvt_whh(const float* __restrict__ in,
                                                   _Float16* __restrict__ out){
  int i = blockIdx.x * 256 + threadIdx.x;   // grid sized exactly 1536*512
  out[i] = (_Float16)in[i];
}

// --- K1: x_gates = emb[seq] @ w_ih^T + b_ih, stored bf16 as [b][s][1536] ---
// Block = 256 thr (4 waves); tile: one s (64 batch rows) x 64 gate cols.
// K=256 split in 2 panels of 128 -> 32 KB LDS. f32 global loads converted to
// bf16 (RNE) at staging. XOR chunk swizzle breaks power-of-2 bank strides.
#define LDSIDX2(row, chunk) (((row) << 7) + ((((chunk) ^ ((row) & 7))) << 3))
__global__ __launch_bounds__(256) void gru_xgates(
    const int* __restrict__ seq, const float* __restrict__ emb,
    const float* __restrict__ w_ih, const float* __restrict__ b_ih,
    ushort_t* __restrict__ xg)
{
  __shared__ __align__(16) short lA[64 * 128];
  __shared__ __align__(16) short lB[64 * 128];
  const int tid   = threadIdx.x;
  const int sIdx  = blockIdx.x;        // one s per block (m = batch)
  const int nBase = blockIdx.y * 64;
  const int w    = tid >> 6;
  const int l    = tid & 63;
  const int l15  = l & 15;
  const int quad = l >> 4;
  floatx4 acc[4] = {};

  #pragma unroll
  for (int kp = 0; kp < 2; ++kp){      // K panel: [kp*128, kp*128+128)
    __syncthreads();                   // previous panel's reads all done
    #pragma unroll
    for (int i = 0; i < 4; ++i){
      int lin = i * 256 + tid;         // [0,1024)
      int row = lin >> 4;              // [0,64)
      int kc  = lin & 15;              // 8-elem chunk within panel
      int kbase = kp * 128 + kc * 8;
      int token = seq[(sIdx << 6) + row];
      const float* srcA = emb  + (size_t)token * EMBD + kbase;
      const float* srcB = w_ih + (size_t)(nBase + row) * EMBD + kbase;
      floatx4 a0 = *(const floatx4*)(srcA);
      floatx4 a1 = *(const floatx4*)(srcA + 4);
      floatx4 b0 = *(const floatx4*)(srcB);
      floatx4 b1 = *(const floatx4*)(srcB + 4);
      short8 pa, pb;
      #pragma unroll
      for (int j = 0; j < 4; ++j){
        pa[j]     = (short)f2bf(a0[j]);
        pa[j + 4] = (short)f2bf(a1[j]);
        pb[j]     = (short)f2bf(b0[j]);
        pb[j + 4] = (short)f2bf(b1[j]);
      }
      *(short8*)&lA[LDSIDX2(row, kc)] = pa;
      *(short8*)&lB[LDSIDX2(row, kc)] = pb;
    }
    __syncthreads();
    #pragma unroll
    for (int kc = 0; kc < 4; ++kc){
      int chunk = kc * 4 + quad;       // lane holds k = chunk*8 + j (A layout)
      short8 a = *(const short8*)&lA[LDSIDX2(w * 16 + l15, chunk)];
      #pragma unroll
      for (int s = 0; s < 4; ++s){
        short8 bf = *(const short8*)&lB[LDSIDX2(s * 16 + l15, chunk)];
        acc[s] = __builtin_amdgcn_mfma_f32_16x16x32_bf16(a, bf, acc[s], 0, 0, 0);
      }
    }
  }
  // C/D layout: col = lane&15 (n=gate), row = quad*4 + reg (m=batch).
  #pragma unroll
  for (int s = 0; s < 4; ++s){
    int g = nBase + s * 16 + l15;
    float bias = b_ih[g];
    #pragma unroll
    for (int r = 0; r < 4; ++r){
      int bIdx = w * 16 + quad * 4 + r;
      xg[((size_t)bIdx * SEQL + sIdx) * G3 + g] = f2bf(acc[s][r] + bias);
    }
  }
}

// --- K2: recurrence. 64 blocks (one sequence each) x 256 threads. ---
// Thread owns gate rows {tid + 256*i, i=0..5} = r,z,n for j in {tid, tid+256},
// so it also owns h[tid], h[tid+256]. h mirrored in LDS as f16 for the matvec.
__global__ __launch_bounds__(256) void gru_rec(
    const ushort_t* __restrict__ xg, const _Float16* __restrict__ whh,
    const float* __restrict__ bhh, const float* __restrict__ wout,
    const float* __restrict__ bout, const int* __restrict__ lengths,
    float* __restrict__ out)
{
  __shared__ __align__(16) _Float16 hsh[HID];
  __shared__ float red[NOUT][4];
  const int b   = blockIdx.x;
  const int tid = threadIdx.x;
  const int L   = lengths[b];
  hsh[tid]       = (_Float16)0.f;
  hsh[tid + 256] = (_Float16)0.f;
  float h0 = 0.f, h1 = 0.f;
  float bias[6];
  const _Float16* wp[6];
  #pragma unroll
  for (int i = 0; i < 6; ++i){
    int row = i * 256 + tid;
    bias[i] = bhh[row];
    wp[i]   = whh + (size_t)row * HID;
  }
  const ushort_t* xrow = xg + (size_t)b * SEQL * G3;
  __syncthreads();

  for (int t = 0; t < L; ++t){
    float acc[6] = {0.f, 0.f, 0.f, 0.f, 0.f, 0.f};
    #pragma unroll 4
    for (int kc = 0; kc < 64; ++kc){
      half8 hv = *(const half8*)&hsh[kc * 8];          // uniform addr: broadcast
      half2v h01 = __builtin_shufflevector(hv, hv, 0, 1);
      half2v h23 = __builtin_shufflevector(hv, hv, 2, 3);
      half2v h45 = __builtin_shufflevector(hv, hv, 4, 5);
      half2v h67 = __builtin_shufflevector(hv, hv, 6, 7);
      #pragma unroll
      for (int i = 0; i < 6; ++i){
        half8 wv = *(const half8*)(wp[i] + (kc << 3)); // 16B per stream
        float a = acc[i];
        a = dot2f(__builtin_shufflevector(wv, wv, 0, 1), h01, a);
        a = dot2f(__builtin_shufflevector(wv, wv, 2, 3), h23, a);
        a = dot2f(__builtin_shufflevector(wv, wv, 4, 5), h45, a);
        a = dot2f(__builtin_shufflevector(wv, wv, 6, 7), h67, a);
        acc[i] = a;
      }
    }
    __syncthreads();   // all matvec reads of hsh done before overwrite
    const ushort_t* xt = xrow + (size_t)t * G3;
    float xr0 = bf2f(xt[tid]),        xr1 = bf2f(xt[tid + 256]);
    float xz0 = bf2f(xt[512 + tid]),  xz1 = bf2f(xt[768 + tid]);
    float xn0 = bf2f(xt[1024 + tid]), xn1 = bf2f(xt[1280 + tid]);
    float r0 = sigm(xr0 + acc[0] + bias[0]);
    float r1 = sigm(xr1 + acc[1] + bias[1]);
    float z0 = sigm(xz0 + acc[2] + bias[2]);
    float z1 = sigm(xz1 + acc[3] + bias[3]);
    float n0 = tanh_c(xn0 + r0 * (acc[4] + bias[4]));  // b_hh_n inside r*(...)
    float n1 = tanh_c(xn1 + r1 * (acc[5] + bias[5]));
    h0 = (1.f - z0) * n0 + z0 * h0;
    h1 = (1.f - z1) * n1 + z1 * h1;
    hsh[tid]       = (_Float16)h0;
    hsh[tid + 256] = (_Float16)h1;
    __syncthreads();
  }

  // logits = h @ w_out^T + b_out ; log_softmax; f32 out
  float p[NOUT];
  #pragma unroll
  for (int o = 0; o < NOUT; ++o){
    p[o] = wout[o * HID + tid] * h0 + wout[o * HID + tid + 256] * h1;
    #pragma unroll
    for (int d = 32; d >= 1; d >>= 1) p[o] += __shfl_down(p[o], d, 64);
  }
  const int wv_i = tid >> 6;
  if ((tid & 63) == 0){
    #pragma unroll
    for (int o = 0; o < NOUT; ++o) red[o][wv_i] = p[o];
  }
  __syncthreads();
  if (tid == 0){
    float lg[NOUT], m = -1e30f;
    #pragma unroll
    for (int o = 0; o < NOUT; ++o){
      float v = red[o][0] + red[o][1] + red[o][2] + red[o][3] + bout[o];
      if (!(v == v)) v = -1.0f;   // NaN guard: make dtype-misread distinguishable
      lg[o] = v;
      m = fmaxf(m, v);
    }
    float ssum = 0.f;
    #pragma unroll
    for (int o = 0; o < NOUT; ++o) ssum += __expf(lg[o] - m);
    float ls = __logf(ssum);
    #pragma unroll
    for (int o = 0; o < NOUT; ++o) out[b * NOUT + o] = lg[o] - m - ls;
  }
}

extern "C" void kernel_launch(void* const* d_in, const int* in_sizes, int n_in,
                              void* d_out, int out_size, void* d_ws, size_t ws_size,
                              hipStream_t stream) {
  (void)in_sizes; (void)n_in; (void)out_size; (void)ws_size;
  const int*   seq     = (const int*)d_in[0];
  const int*   lengths = (const int*)d_in[1];
  const float* emb     = (const float*)d_in[2];
  const float* w_ih    = (const float*)d_in[3];
  const float* w_hh    = (const float*)d_in[4];
  const float* b_ih    = (const float*)d_in[5];
  const float* b_hh    = (const float*)d_in[6];
  const float* w_out   = (const float*)d_in[7];
  const float* b_out   = (const float*)d_in[8];
  float*       outp    = (float*)d_out;

  char* ws = (char*)d_ws;
  ushort_t* xg     = (ushort_t*)ws;                                   // 100,663,296 B
  _Float16* whh16  = (_Float16*)(ws + (size_t)BATCH * SEQL * G3 * 2); // 1,572,864 B

  gru_cvt_whh<<<(G3 * HID) / 256, 256, 0, stream>>>(w_hh, whh16);
  dim3 g1(SEQL, G3 / 64);
  gru_xgates<<<g1, 256, 0, stream>>>(seq, emb, w_ih, b_ih, xg);
  gru_rec<<<BATCH, 256, 0, stream>>>(xg, whh16, b_hh, w_out, b_out, lengths, outp);
}

// Round 3
// 3888.766 us; speedup vs baseline: 5.5529x; 5.5529x over previous
//
#include <hip/hip_runtime.h>

// ---------------------------------------------------------------------------
// SimpleGRU on MI355X (gfx950). Round 3: grid-resident recurrence.
//   Round-2 failure mode: batch-split gru_rec was L1-transaction-bound
//   (1KB-strided 16B gathers, 96MB/step aggregate weight re-reads) -> 21.6ms.
//   Now: 32 blocks (1/CU, co-resident), block g owns hidden slice [16g,16g+16).
//   W_hh rows for the slice live in 192 VGPRs as MFMA B-frags (loaded once).
//   Per step: H (64x512 f16) staged to LDS via agent-scope coherent loads,
//   mfma_f32_16x16x32_f16 (M=64 batch, N=48 gates, K=512), f32 h-carry,
//   coherent stores + flag release/spin, double-buffered H.
// ws: xg bf16 [512][1536][64] | whh f16 [1536][512] | hbuf f16 [2][64][512]
//     | flags int[32]
// ---------------------------------------------------------------------------

typedef unsigned short ushort_t;
typedef short short8      __attribute__((ext_vector_type(8)));
typedef float floatx4     __attribute__((ext_vector_type(4)));
typedef unsigned int uintx4 __attribute__((ext_vector_type(4)));
typedef unsigned short ushort4v __attribute__((ext_vector_type(4)));
typedef _Float16 half8    __attribute__((ext_vector_type(8)));

#define SEQL 512
#define BATCH 64
#define EMBD 256
#define HID 512
#define G3 1536
#define NOUT 5
#define NBLK 32            // hidden-split blocks, 1 per CU, co-resident

__device__ __forceinline__ float bf2f(ushort_t v){
  union { unsigned u; float f; } x; x.u = ((unsigned)v) << 16; return x.f;
}
__device__ __forceinline__ ushort_t f2bf(float f){
  unsigned u = __float_as_uint(f);
  return (ushort_t)((u + 0x7FFFu + ((u >> 16) & 1u)) >> 16);
}
__device__ __forceinline__ float sigm(float x){
  x = fminf(fmaxf(x, -20.f), 20.f);
  return 1.f / (1.f + __expf(-x));
}
__device__ __forceinline__ float tanh_c(float x){
  x = fminf(fmaxf(x, -10.f), 10.f);
  float e = __expf(2.f * x);
  return (e - 1.f) / (e + 1.f);
}

// --- K0a: zero hbuf (2*64*512 f16) + flags(32) ---
__global__ __launch_bounds__(256) void gru_init(unsigned long long* __restrict__ hbuf8,
                                                int* __restrict__ flags){
  int i = blockIdx.x * 256 + threadIdx.x;       // grid 64 -> 16384 thr * 8B = 128KB
  hbuf8[i] = 0ull;
  if (blockIdx.x == 0 && threadIdx.x < NBLK) flags[threadIdx.x] = 0;
}

// --- K0b: convert w_hh f32 -> f16 ---
__global__ __launch_bounds__(256) void gru_cvt_whh(const float* __restrict__ in,
                                                   _Float16* __restrict__ out){
  int i = blockIdx.x * 256 + threadIdx.x;       // grid 3072
  out[i] = (_Float16)in[i];
}

// --- K1: x_gates = emb[seq] @ w_ih^T + b_ih, bf16, layout [s][1536][64] ---
#define LDSIDX2(row, chunk) (((row) << 7) + ((((chunk) ^ ((row) & 7))) << 3))
__global__ __launch_bounds__(256) void gru_xgates(
    const int* __restrict__ seq, const float* __restrict__ emb,
    const float* __restrict__ w_ih, const float* __restrict__ b_ih,
    ushort_t* __restrict__ xg)
{
  __shared__ __align__(16) short lA[64 * 128];
  __shared__ __align__(16) short lB[64 * 128];
  const int tid   = threadIdx.x;
  const int sIdx  = blockIdx.x;
  const int nBase = blockIdx.y * 64;
  const int w    = tid >> 6;
  const int l    = tid & 63;
  const int l15  = l & 15;
  const int quad = l >> 4;
  floatx4 acc[4] = {};

  #pragma unroll
  for (int kp = 0; kp < 2; ++kp){
    __syncthreads();
    #pragma unroll
    for (int i = 0; i < 4; ++i){
      int lin = i * 256 + tid;
      int row = lin >> 4;
      int kc  = lin & 15;
      int kbase = kp * 128 + kc * 8;
      int token = seq[(sIdx << 6) + row];
      const float* srcA = emb  + (size_t)token * EMBD + kbase;
      const float* srcB = w_ih + (size_t)(nBase + row) * EMBD + kbase;
      floatx4 a0 = *(const floatx4*)(srcA);
      floatx4 a1 = *(const floatx4*)(srcA + 4);
      floatx4 b0 = *(const floatx4*)(srcB);
      floatx4 b1 = *(const floatx4*)(srcB + 4);
      short8 pa, pb;
      #pragma unroll
      for (int j = 0; j < 4; ++j){
        pa[j]     = (short)f2bf(a0[j]);
        pa[j + 4] = (short)f2bf(a1[j]);
        pb[j]     = (short)f2bf(b0[j]);
        pb[j + 4] = (short)f2bf(b1[j]);
      }
      *(short8*)&lA[LDSIDX2(row, kc)] = pa;
      *(short8*)&lB[LDSIDX2(row, kc)] = pb;
    }
    __syncthreads();
    #pragma unroll
    for (int kc = 0; kc < 4; ++kc){
      int chunk = kc * 4 + quad;
      short8 a = *(const short8*)&lA[LDSIDX2(w * 16 + l15, chunk)];
      #pragma unroll
      for (int s = 0; s < 4; ++s){
        short8 bf = *(const short8*)&lB[LDSIDX2(s * 16 + l15, chunk)];
        acc[s] = __builtin_amdgcn_mfma_f32_16x16x32_bf16(a, bf, acc[s], 0, 0, 0);
      }
    }
  }
  // C/D: col=lane&15 (g within 16), row=quad*4+reg (batch). Store b-fastest.
  #pragma unroll
  for (int s = 0; s < 4; ++s){
    int g = nBase + s * 16 + l15;
    float bias = b_ih[g];
    ushort4v pk;
    #pragma unroll
    for (int r = 0; r < 4; ++r) pk[r] = f2bf(acc[s][r] + bias);
    *(ushort4v*)(xg + ((size_t)sIdx * G3 + g) * BATCH + (w * 16 + quad * 4)) = pk;
  }
}

// --- K2: grid-resident recurrence. 32 blocks x 256 threads (1 block/CU). ---
__global__ __launch_bounds__(256, 1) void gru_rec(
    const ushort_t* __restrict__ xg, const _Float16* __restrict__ whh,
    const float* __restrict__ bhh, const int* __restrict__ lengths,
    _Float16* __restrict__ hbuf, int* __restrict__ flags)
{
  __shared__ __align__(16) _Float16 hlds[BATCH * HID];   // 64KB, 16B-chunk XOR swizzle
  const int g    = blockIdx.x;          // hidden slice [g*16, g*16+16)
  const int tid  = threadIdx.x;
  const int w    = tid >> 6;
  const int l    = tid & 63;
  const int l15  = l & 15;
  const int quad = l >> 4;
  const int j    = g * 16 + l15;        // this lane's hidden unit
  const int bbase = w * 16 + quad * 4;  // this lane's 4 batches

  // --- one-time: W_hh B-fragments into registers (48 frags x 4 VGPR = 192) ---
  half8 bR[16], bZ[16], bN[16];
  {
    const _Float16* pR = whh + (size_t)(       j) * HID + quad * 8;
    const _Float16* pZ = whh + (size_t)(HID  + j) * HID + quad * 8;
    const _Float16* pN = whh + (size_t)(2*HID+ j) * HID + quad * 8;
    #pragma unroll
    for (int ks = 0; ks < 16; ++ks){
      bR[ks] = *(const half8*)(pR + ks * 32);
      bZ[ks] = *(const half8*)(pZ + ks * 32);
      bN[ks] = *(const half8*)(pN + ks * 32);
    }
  }
  const float bhR = bhh[j], bhZ = bhh[HID + j], bhN = bhh[2 * HID + j];
  int   len[4];
  float h[4];
  #pragma unroll
  for (int r = 0; r < 4; ++r){ len[r] = lengths[bbase + r]; h[r] = 0.f; }
  const int Lmax = lengths[0];          // sorted descending

  for (int t = 0; t < Lmax; ++t){
    // 1) wait until all blocks have published hbuf[t&1] (t=0: trivially true)
    if (t > 0 && l < NBLK){
      const int* fp = flags + l;
      while (__hip_atomic_load(fp, __ATOMIC_RELAXED, __HIP_MEMORY_SCOPE_AGENT) < t) { }
    }
    __syncthreads();

    // 2) prefetch this lane's xg values (plain cached loads, read-only data)
    const ushort_t* xt = xg + (size_t)t * G3 * BATCH;
    ushort4v xR = *(const ushort4v*)(xt + (size_t)(        j) * BATCH + bbase);
    ushort4v xZ = *(const ushort4v*)(xt + (size_t)(HID   + j) * BATCH + bbase);
    ushort4v xN = *(const ushort4v*)(xt + (size_t)(2*HID + j) * BATCH + bbase);

    // 3) stage hbuf[t&1] -> LDS (agent-scope coherent loads; XOR-swizzled 16B chunks)
    const _Float16* hsrc = hbuf + (size_t)(t & 1) * BATCH * HID;
    #pragma unroll
    for (int i = 0; i < 16; ++i){
      int m  = i * 4 + w;               // row (batch)
      int kc = l;                       // 16B chunk 0..63
      unsigned long long* src = (unsigned long long*)(hsrc + (size_t)m * HID + kc * 8);
      unsigned long long lo = __hip_atomic_load(src,     __ATOMIC_RELAXED, __HIP_MEMORY_SCOPE_AGENT);
      unsigned long long hi = __hip_atomic_load(src + 1, __ATOMIC_RELAXED, __HIP_MEMORY_SCOPE_AGENT);
      int kcs = kc ^ (m & 7);
      unsigned long long* dst = (unsigned long long*)(hlds + (size_t)m * HID + kcs * 8);
      dst[0] = lo; dst[1] = hi;
    }
    __syncthreads();

    // 4) MFMA: acc(m-tile w, 3 gate n-tiles), K=512
    floatx4 aR = {0.f,0.f,0.f,0.f}, aZ = {0.f,0.f,0.f,0.f}, aN = {0.f,0.f,0.f,0.f};
    #pragma unroll
    for (int ks = 0; ks < 16; ++ks){
      int kcs = (ks * 4 + quad) ^ (l15 & 7);
      half8 a = *(const half8*)(hlds + (size_t)(w * 16 + l15) * HID + kcs * 8);
      aR = __builtin_amdgcn_mfma_f32_16x16x32_f16(a, bR[ks], aR, 0, 0, 0);
      aZ = __builtin_amdgcn_mfma_f32_16x16x32_f16(a, bZ[ks], aZ, 0, 0, 0);
      aN = __builtin_amdgcn_mfma_f32_16x16x32_f16(a, bN[ks], aN, 0, 0, 0);
    }

    // 5) gates + h update (f32 carry) + coherent f16 store of h_new
    _Float16* hdst = hbuf + (size_t)((t + 1) & 1) * BATCH * HID;
    #pragma unroll
    for (int r = 0; r < 4; ++r){
      float rr = sigm(bf2f(xR[r]) + aR[r] + bhR);
      float zz = sigm(bf2f(xZ[r]) + aZ[r] + bhZ);
      float nn = tanh_c(bf2f(xN[r]) + rr * (aN[r] + bhN));
      float hn = (1.f - zz) * nn + zz * h[r];
      h[r] = (t < len[r]) ? hn : h[r];
      union { _Float16 hf; unsigned short us; } cv; cv.hf = (_Float16)h[r];
      __hip_atomic_store((unsigned short*)(hdst + (size_t)(bbase + r) * HID + j),
                         cv.us, __ATOMIC_RELAXED, __HIP_MEMORY_SCOPE_AGENT);
    }
    __syncthreads();   // drains vmcnt: all this block's h stores complete
    if (tid == 0)
      __hip_atomic_store(flags + g, t + 1, __ATOMIC_RELEASE, __HIP_MEMORY_SCOPE_AGENT);
  }
}

// --- K3: logits + log_softmax. 64 blocks x 64 threads (1 wave). ---
__global__ __launch_bounds__(64) void gru_out(
    const _Float16* __restrict__ hbuf, const int* __restrict__ lengths,
    const float* __restrict__ wout, const float* __restrict__ bout,
    float* __restrict__ out)
{
  const int b = blockIdx.x, l = threadIdx.x;
  const _Float16* h = hbuf + (size_t)(lengths[0] & 1) * BATCH * HID + (size_t)b * HID;
  half8 hv = *(const half8*)(h + l * 8);
  float p[NOUT];
  #pragma unroll
  for (int o = 0; o < NOUT; ++o){
    const float* wr = wout + o * HID + l * 8;
    float a = 0.f;
    #pragma unroll
    for (int i = 0; i < 8; ++i) a += wr[i] * (float)hv[i];
    #pragma unroll
    for (int d = 32; d >= 1; d >>= 1) a += __shfl_down(a, d, 64);
    p[o] = a;
  }
  if (l == 0){
    float lg[NOUT], m = -1e30f;
    #pragma unroll
    for (int o = 0; o < NOUT; ++o){ lg[o] = p[o] + bout[o]; m = fmaxf(m, lg[o]); }
    float ssum = 0.f;
    #pragma unroll
    for (int o = 0; o < NOUT; ++o) ssum += __expf(lg[o] - m);
    float ls = __logf(ssum);
    #pragma unroll
    for (int o = 0; o < NOUT; ++o) out[b * NOUT + o] = lg[o] - m - ls;
  }
}

extern "C" void kernel_launch(void* const* d_in, const int* in_sizes, int n_in,
                              void* d_out, int out_size, void* d_ws, size_t ws_size,
                              hipStream_t stream) {
  (void)in_sizes; (void)n_in; (void)out_size; (void)ws_size;
  const int*   seq     = (const int*)d_in[0];
  const int*   lengths = (const int*)d_in[1];
  const float* emb     = (const float*)d_in[2];
  const float* w_ih    = (const float*)d_in[3];
  const float* w_hh    = (const float*)d_in[4];
  const float* b_ih    = (const float*)d_in[5];
  const float* b_hh    = (const float*)d_in[6];
  const float* w_out   = (const float*)d_in[7];
  const float* b_out   = (const float*)d_in[8];
  float*       outp    = (float*)d_out;

  char* ws = (char*)d_ws;
  ushort_t* xg    = (ushort_t*)ws;                               // 100,663,296 B
  _Float16* whh16 = (_Float16*)(ws + 100663296);                 //   1,572,864 B
  _Float16* hbuf  = (_Float16*)(ws + 100663296 + 1572864);       //     131,072 B
  int*      flags = (int*)     (ws + 100663296 + 1572864 + 131072);

  gru_init<<<64, 256, 0, stream>>>((unsigned long long*)hbuf, flags);
  gru_cvt_whh<<<(G3 * HID) / 256, 256, 0, stream>>>(w_hh, whh16);
  dim3 g1(SEQL, G3 / 64);
  gru_xgates<<<g1, 256, 0, stream>>>(seq, emb, w_ih, b_ih, xg);
  gru_rec<<<NBLK, 256, 0, stream>>>(xg, whh16, b_hh, lengths, hbuf, flags);
  gru_out<<<BATCH, 64, 0, stream>>>(hbuf, lengths, w_out, b_out, outp);
}